// Round 1
// baseline (842.470 us; speedup 1.0000x reference)
//
#include <hip/hip_runtime.h>
#include <math.h>

#define N_NODES 50000
#define E_EDGES 800000
#define D_FEAT  64
#define C_CH    3
#define H_HID   8
#define OUT_F   128
#define CD      (C_CH * D_FEAT)   // 192

__device__ __forceinline__ float lrelu(float v) { return v >= 0.f ? v : 0.01f * v; }

// --- K1: fused edge-MLP + weighted scatter-add ------------------------------
// one wave (64 lanes) per edge; lane = feature d
__global__ __launch_bounds__(256) void k_scatter(
    const float* __restrict__ x, const int* __restrict__ ei,
    const float* __restrict__ ea,
    const float* __restrict__ w1, const float* __restrict__ b1,
    const float* __restrict__ w2, const float* __restrict__ b2,
    float* __restrict__ agg)
{
    int e = blockIdx.x * 4 + (threadIdx.x >> 6);
    if (e >= E_EDGES) return;
    int lane = threadIdx.x & 63;

    int src = ei[e];
    int dst = ei[E_EDGES + e];
    float a = ea[e];

    float wc[C_CH];
#pragma unroll
    for (int c = 0; c < C_CH; ++c) {
        float s = 0.f;
#pragma unroll
        for (int h = 0; h < H_HID; ++h) {
            float t = fmaf(a, w1[c * H_HID + h], b1[c * H_HID + h]);
            t = (t >= 0.f) ? t : 0.01f * t;               // leaky_relu
            s = fmaf(t, w2[c * H_HID + h], s);
        }
        s += b2[c];
        wc[c] = (s > 0.f) ? s : expm1f(s);                // elu (alpha=1)
    }

    float xj = x[(size_t)src * D_FEAT + lane];
    float* aggrow = agg + (size_t)dst * CD + lane;
#pragma unroll
    for (int c = 0; c < C_CH; ++c)
        atomicAdd(aggrow + c * D_FEAT, wc[c] * xj);
}

// --- K2: residual + layer1 of node MLP (W1 in LDS, 98 KB) -------------------
// 256 threads = 2 nodes x 128 output columns
__global__ __launch_bounds__(256) void k_mlp1(
    const float* __restrict__ agg, const float* __restrict__ x,
    const float* __restrict__ eps,
    const float* __restrict__ nw1, const float* __restrict__ nb1,
    float* __restrict__ mid)
{
    __shared__ float W[CD * OUT_F];     // 98304 B
    __shared__ float v[2][CD];

    const int tid = threadIdx.x;
    for (int i = tid; i < CD * OUT_F / 4; i += 256)
        ((float4*)W)[i] = ((const float4*)nw1)[i];

    const float e0 = 1.f + eps[0], e1 = 1.f + eps[1], e2 = 1.f + eps[2];
    const int nl = tid >> 7;            // which of the 2 nodes
    const int o  = tid & 127;           // output column
    const float bias = nb1[o];
    const int NPAIR = N_NODES / 2;      // N even

    for (int p = blockIdx.x; p < NPAIR; p += gridDim.x) {
        __syncthreads();                // protect v of previous iteration
        for (int idx = tid; idx < 2 * CD; idx += 256) {
            int vnl = idx / CD, k = idx % CD;
            int n = 2 * p + vnl;
            int c = k >> 6, d = k & 63;
            float ec = (c == 0) ? e0 : (c == 1 ? e1 : e2);
            v[vnl][k] = agg[(size_t)n * CD + k] + ec * x[(size_t)n * D_FEAT + d];
        }
        __syncthreads();
        int n = 2 * p + nl;
        float acc = bias;
#pragma unroll 8
        for (int k = 0; k < CD; ++k)
            acc = fmaf(v[nl][k], W[k * OUT_F + o], acc);
        mid[(size_t)n * OUT_F + o] = lrelu(acc);
    }
}

// --- K3: layer2 of node MLP, in-place on d_out (W2 in LDS, 64 KB) -----------
__global__ __launch_bounds__(256) void k_mlp2(
    const float* __restrict__ nw2, const float* __restrict__ nb2,
    float* __restrict__ out)
{
    __shared__ float W[OUT_F * OUT_F];  // 65536 B
    __shared__ float m[2][OUT_F];

    const int tid = threadIdx.x;
    for (int i = tid; i < OUT_F * OUT_F / 4; i += 256)
        ((float4*)W)[i] = ((const float4*)nw2)[i];

    const int nl = tid >> 7, o = tid & 127;
    const float bias = nb2[o];
    const int NPAIR = N_NODES / 2;

    for (int p = blockIdx.x; p < NPAIR; p += gridDim.x) {
        __syncthreads();                // protect m of previous iteration
        int n = 2 * p + nl;
        m[nl][o] = out[(size_t)n * OUT_F + o];
        __syncthreads();
        float acc = bias;
#pragma unroll 8
        for (int k = 0; k < OUT_F; ++k)
            acc = fmaf(m[nl][k], W[k * OUT_F + o], acc);
        out[(size_t)n * OUT_F + o] = acc;
    }
}

extern "C" void kernel_launch(void* const* d_in, const int* in_sizes, int n_in,
                              void* d_out, int out_size, void* d_ws, size_t ws_size,
                              hipStream_t stream)
{
    const float* x    = (const float*)d_in[0];
    const int*   ei   = (const int*)  d_in[1];
    const float* ea   = (const float*)d_in[2];
    const float* w1   = (const float*)d_in[3];
    const float* b1   = (const float*)d_in[4];
    const float* w2   = (const float*)d_in[5];
    const float* b2   = (const float*)d_in[6];
    const float* eps  = (const float*)d_in[7];
    const float* nw1  = (const float*)d_in[8];
    const float* nb1  = (const float*)d_in[9];
    const float* nw2  = (const float*)d_in[10];
    const float* nb2  = (const float*)d_in[11];
    float* out = (float*)d_out;
    float* agg = (float*)d_ws;                       // N*CD floats = 38.4 MB

    size_t agg_bytes = (size_t)N_NODES * CD * sizeof(float);
    hipMemsetAsync(d_ws, 0, agg_bytes, stream);

    k_scatter<<<(E_EDGES + 3) / 4, 256, 0, stream>>>(x, ei, ea, w1, b1, w2, b2, agg);
    k_mlp1<<<256, 256, 0, stream>>>(agg, x, eps, nw1, nb1, out);
    k_mlp2<<<512, 256, 0, stream>>>(nw2, nb2, out);
}

// Round 2
// 527.764 us; speedup vs baseline: 1.5963x; 1.5963x over previous
//
#include <hip/hip_runtime.h>
#include <math.h>

#define N_NODES 50000
#define E_EDGES 800000
#define D_FEAT  64
#define C_CH    3
#define H_HID   8
#define OUT_F   128
#define CD      192              // C*D
#define NTILES  (N_NODES / 16)   // 3125 exact

typedef _Float16 half8 __attribute__((ext_vector_type(8)));
typedef float f32x4 __attribute__((ext_vector_type(4)));

__device__ __forceinline__ float lrelu(float v) { return v >= 0.f ? v : 0.01f * v; }

// --- K0: edge MLP -> per-edge channel weights (1 thread / edge) -------------
__global__ __launch_bounds__(256) void k_edgew(
    const float* __restrict__ ea,
    const float* __restrict__ w1, const float* __restrict__ b1,
    const float* __restrict__ w2, const float* __restrict__ b2,
    float4* __restrict__ wbuf)
{
    int e = blockIdx.x * 256 + threadIdx.x;
    if (e >= E_EDGES) return;
    float a = ea[e];
    float wc[C_CH];
#pragma unroll
    for (int c = 0; c < C_CH; ++c) {
        float s = 0.f;
#pragma unroll
        for (int h = 0; h < H_HID; ++h) {
            float t = fmaf(a, w1[c * H_HID + h], b1[c * H_HID + h]);
            t = (t >= 0.f) ? t : 0.01f * t;               // leaky_relu
            s = fmaf(t, w2[c * H_HID + h], s);
        }
        s += b2[c];
        wc[c] = (s > 0.f) ? s : expm1f(s);                // elu
    }
    wbuf[e] = make_float4(wc[0], wc[1], wc[2], 0.f);
}

// --- K1: slim weighted scatter-add (wave per edge, lane = feature) ----------
__global__ __launch_bounds__(256) void k_scatter(
    const float* __restrict__ x, const int* __restrict__ ei,
    const float4* __restrict__ wbuf, float* __restrict__ agg)
{
    int e = blockIdx.x * 4 + (threadIdx.x >> 6);   // E divisible by 4
    int lane = threadIdx.x & 63;
    int src = ei[e];
    int dst = ei[E_EDGES + e];
    float4 w = wbuf[e];
    float xj = x[(size_t)src * D_FEAT + lane];
    float* p = agg + (size_t)dst * CD + lane;
    atomicAdd(p,       w.x * xj);
    atomicAdd(p + 64,  w.y * xj);
    atomicAdd(p + 128, w.z * xj);
}

// --- K2: fused residual + MLP1(lrelu) + MLP2 via f16 MFMA -------------------
// block = 256 thr = 4 waves; each block-iter handles 16 nodes x 128 outs.
// wave w owns output cols [32w, 32w+32). Weights live in per-lane B-frags.
__global__ __launch_bounds__(256) void k_mlp(
    const float* __restrict__ agg, const float* __restrict__ x,
    const float* __restrict__ eps,
    const float* __restrict__ nw1, const float* __restrict__ nb1,
    const float* __restrict__ nw2, const float* __restrict__ nb2,
    float* __restrict__ out)
{
    __shared__ _Float16 vtile[16][CD + 8];     // stride 200 f16 = 400B (16B mult)
    __shared__ _Float16 htile[16][OUT_F + 8];  // stride 136 f16 = 272B (16B mult)

    const int tid  = threadIdx.x;
    const int lane = tid & 63;
    const int wid  = tid >> 6;
    const int arow = lane & 15;        // A row / C col within 16
    const int kg   = lane >> 4;        // k-group (8 k's each)
    const int o0   = wid * 32;         // this wave's first output col

    // ---- load weight B-fragments into registers (once per block) ----
    half8 w1f[6][2], w2f[4][2];
#pragma unroll
    for (int kk = 0; kk < 6; ++kk)
#pragma unroll
        for (int nt = 0; nt < 2; ++nt) {
            half8 f;
            int colb = o0 + nt * 16 + arow;
            int kb = kk * 32 + kg * 8;
#pragma unroll
            for (int j = 0; j < 8; ++j)
                f[j] = (_Float16)nw1[(size_t)(kb + j) * OUT_F + colb];
            w1f[kk][nt] = f;
        }
#pragma unroll
    for (int kk = 0; kk < 4; ++kk)
#pragma unroll
        for (int nt = 0; nt < 2; ++nt) {
            half8 f;
            int colb = o0 + nt * 16 + arow;
            int kb = kk * 32 + kg * 8;
#pragma unroll
            for (int j = 0; j < 8; ++j)
                f[j] = (_Float16)nw2[(size_t)(kb + j) * OUT_F + colb];
            w2f[kk][nt] = f;
        }

    const float e0 = 1.f + eps[0], e1 = 1.f + eps[1], e2 = 1.f + eps[2];
    const float b1a = nb1[o0 + arow],      b1b = nb1[o0 + 16 + arow];
    const float b2a = nb2[o0 + arow],      b2b = nb2[o0 + 16 + arow];

    for (int t = blockIdx.x; t < NTILES; t += gridDim.x) {
        const int nb16 = t * 16;
        __syncthreads();   // prev iter fully consumed vtile/htile
        // build v tile: v[n][k] = agg[n][k] + (1+eps_c)*x[n][k&63], as f16
        for (int i = tid; i < 16 * CD; i += 256) {          // 12 iters exact
            int nl = i / CD, k = i % CD;
            int c = k >> 6, d = k & 63;
            float ec = (c == 0) ? e0 : (c == 1 ? e1 : e2);
            float v = agg[(size_t)(nb16 + nl) * CD + k]
                    + ec * x[(size_t)(nb16 + nl) * D_FEAT + d];
            vtile[nl][k] = (_Float16)v;
        }
        __syncthreads();

        // GEMM1: [16x192] x [192x32(this wave)] -> h
        f32x4 acc0 = {0.f, 0.f, 0.f, 0.f}, acc1 = {0.f, 0.f, 0.f, 0.f};
#pragma unroll
        for (int kk = 0; kk < 6; ++kk) {
            half8 a = *(const half8*)&vtile[arow][kk * 32 + kg * 8];
            acc0 = __builtin_amdgcn_mfma_f32_16x16x32_f16(a, w1f[kk][0], acc0, 0, 0, 0);
            acc1 = __builtin_amdgcn_mfma_f32_16x16x32_f16(a, w1f[kk][1], acc1, 0, 0, 0);
        }
        // lrelu + stash h in LDS (C layout: row=kg*4+r, col=o0+arow)
#pragma unroll
        for (int r = 0; r < 4; ++r) {
            int hr = kg * 4 + r;
            htile[hr][o0 + arow]      = (_Float16)lrelu(acc0[r] + b1a);
            htile[hr][o0 + 16 + arow] = (_Float16)lrelu(acc1[r] + b1b);
        }
        __syncthreads();

        // GEMM2: [16x128] x [128x32] -> out
        f32x4 c0 = {0.f, 0.f, 0.f, 0.f}, c1 = {0.f, 0.f, 0.f, 0.f};
#pragma unroll
        for (int kk = 0; kk < 4; ++kk) {
            half8 a = *(const half8*)&htile[arow][kk * 32 + kg * 8];
            c0 = __builtin_amdgcn_mfma_f32_16x16x32_f16(a, w2f[kk][0], c0, 0, 0, 0);
            c1 = __builtin_amdgcn_mfma_f32_16x16x32_f16(a, w2f[kk][1], c1, 0, 0, 0);
        }
#pragma unroll
        for (int r = 0; r < 4; ++r) {
            size_t n = (size_t)(nb16 + kg * 4 + r);
            out[n * OUT_F + o0 + arow]      = c0[r] + b2a;
            out[n * OUT_F + o0 + 16 + arow] = c1[r] + b2b;
        }
    }
}

extern "C" void kernel_launch(void* const* d_in, const int* in_sizes, int n_in,
                              void* d_out, int out_size, void* d_ws, size_t ws_size,
                              hipStream_t stream)
{
    const float* x    = (const float*)d_in[0];
    const int*   ei   = (const int*)  d_in[1];
    const float* ea   = (const float*)d_in[2];
    const float* w1   = (const float*)d_in[3];
    const float* b1   = (const float*)d_in[4];
    const float* w2   = (const float*)d_in[5];
    const float* b2   = (const float*)d_in[6];
    const float* eps  = (const float*)d_in[7];
    const float* nw1  = (const float*)d_in[8];
    const float* nb1  = (const float*)d_in[9];
    const float* nw2  = (const float*)d_in[10];
    const float* nb2  = (const float*)d_in[11];
    float* out = (float*)d_out;
    float* agg = (float*)d_ws;                       // 38.4 MB

    // per-edge weights scratch lives in d_out (12.8 MB <= 25.6 MB),
    // fully overwritten by k_mlp at the end.
    float4* wbuf = (float4*)d_out;

    size_t agg_bytes = (size_t)N_NODES * CD * sizeof(float);
    hipMemsetAsync(d_ws, 0, agg_bytes, stream);

    k_edgew  <<<(E_EDGES + 255) / 256, 256, 0, stream>>>(ea, w1, b1, w2, b2, wbuf);
    k_scatter<<<E_EDGES / 4,          256, 0, stream>>>(x, ei, wbuf, agg);
    k_mlp    <<<768,                  256, 0, stream>>>(agg, x, eps, nw1, nb1, nw2, nb2, out);
}

// Round 3
// 275.710 us; speedup vs baseline: 3.0556x; 1.9142x over previous
//
#include <hip/hip_runtime.h>
#include <math.h>

#define N_NODES 50000
#define E_EDGES 800000
#define D_FEAT  64
#define C_CH    3
#define H_HID   8
#define OUT_F   128
#define CD      192              // C*D
#define NTILES  (N_NODES / 16)   // 3125 exact
#define NBLK_SCAN ((N_NODES + 255) / 256)   // 196

typedef _Float16 half8 __attribute__((ext_vector_type(8)));
typedef float f32x4 __attribute__((ext_vector_type(4)));

__device__ __forceinline__ float lrelu(float v) { return v >= 0.f ? v : 0.01f * v; }

// --- K1: histogram of dst ---------------------------------------------------
__global__ __launch_bounds__(256) void k_hist(
    const int* __restrict__ ei, int* __restrict__ counts)
{
    int e = blockIdx.x * 256 + threadIdx.x;      // grid covers E exactly
    atomicAdd(counts + ei[E_EDGES + e], 1);
}

// --- K2a: per-block sums of counts ------------------------------------------
__global__ __launch_bounds__(256) void k_blocksum(
    const int* __restrict__ counts, int* __restrict__ blocksums)
{
    __shared__ int s[256];
    int i = blockIdx.x * 256 + threadIdx.x;
    s[threadIdx.x] = (i < N_NODES) ? counts[i] : 0;
    __syncthreads();
    for (int off = 128; off >= 1; off >>= 1) {
        if (threadIdx.x < off) s[threadIdx.x] += s[threadIdx.x + off];
        __syncthreads();
    }
    if (threadIdx.x == 0) blocksums[blockIdx.x] = s[0];
}

// --- K2b: exclusive scan of block sums (single block) -----------------------
__global__ __launch_bounds__(256) void k_scanblock(
    const int* __restrict__ blocksums, int* __restrict__ blockoffs)
{
    __shared__ int s[256];
    int tid = threadIdx.x;
    int v = (tid < NBLK_SCAN) ? blocksums[tid] : 0;
    s[tid] = v;
    __syncthreads();
    for (int off = 1; off < 256; off <<= 1) {
        int t = (tid >= off) ? s[tid - off] : 0;
        __syncthreads();
        s[tid] += t;
        __syncthreads();
    }
    if (tid < NBLK_SCAN) blockoffs[tid] = s[tid] - v;   // exclusive
}

// --- K2c: final exclusive scan ----------------------------------------------
__global__ __launch_bounds__(256) void k_scanfinal(
    const int* __restrict__ counts, const int* __restrict__ blockoffs,
    int* __restrict__ offsets)
{
    __shared__ int s[256];
    int tid = threadIdx.x;
    int i = blockIdx.x * 256 + tid;
    int v = (i < N_NODES) ? counts[i] : 0;
    s[tid] = v;
    __syncthreads();
    for (int off = 1; off < 256; off <<= 1) {
        int t = (tid >= off) ? s[tid - off] : 0;
        __syncthreads();
        s[tid] += t;
        __syncthreads();
    }
    if (i < N_NODES) offsets[i] = s[tid] - v + blockoffs[blockIdx.x];
}

// --- K3: edge MLP + placement into dst-sorted record array ------------------
// after this kernel, offsets[n] has become the END offset of node n.
__global__ __launch_bounds__(256) void k_place(
    const int* __restrict__ ei, const float* __restrict__ ea,
    const float* __restrict__ w1, const float* __restrict__ b1,
    const float* __restrict__ w2, const float* __restrict__ b2,
    int* __restrict__ offsets, float4* __restrict__ sorted)
{
    int e = blockIdx.x * 256 + threadIdx.x;
    int src = ei[e];
    int dst = ei[E_EDGES + e];
    float a = ea[e];
    float wc[C_CH];
#pragma unroll
    for (int c = 0; c < C_CH; ++c) {
        float s = 0.f;
#pragma unroll
        for (int h = 0; h < H_HID; ++h) {
            float t = fmaf(a, w1[c * H_HID + h], b1[c * H_HID + h]);
            t = (t >= 0.f) ? t : 0.01f * t;               // leaky_relu
            s = fmaf(t, w2[c * H_HID + h], s);
        }
        s += b2[c];
        wc[c] = (s > 0.f) ? s : expm1f(s);                // elu
    }
    int pos = atomicAdd(offsets + dst, 1);
    sorted[pos] = make_float4(__int_as_float(src), wc[0], wc[1], wc[2]);
}

// --- K4: fused gather + residual + MLP1(lrelu) + MLP2 via f16 MFMA ----------
// block = 256 thr = 4 waves; 16 nodes per tile; wave w gathers 4 nodes.
__global__ __launch_bounds__(256) void k_gmlp(
    const float4* __restrict__ sorted, const int* __restrict__ endoff,
    const float* __restrict__ x, const float* __restrict__ eps,
    const float* __restrict__ nw1, const float* __restrict__ nb1,
    const float* __restrict__ nw2, const float* __restrict__ nb2,
    float* __restrict__ out)
{
    __shared__ _Float16 vtile[16][CD + 8];     // stride 400B (16B mult)
    __shared__ _Float16 htile[16][OUT_F + 8];  // stride 272B (16B mult)

    const int tid  = threadIdx.x;
    const int lane = tid & 63;
    const int wid  = tid >> 6;
    const int arow = lane & 15;        // A row / C col within 16
    const int kg   = lane >> 4;        // k-group (8 k's each)
    const int o0   = wid * 32;         // this wave's first output col

    // ---- weight B-fragments into registers (once per block) ----
    half8 w1f[6][2], w2f[4][2];
#pragma unroll
    for (int kk = 0; kk < 6; ++kk)
#pragma unroll
        for (int nt = 0; nt < 2; ++nt) {
            half8 f;
            int colb = o0 + nt * 16 + arow;
            int kb = kk * 32 + kg * 8;
#pragma unroll
            for (int j = 0; j < 8; ++j)
                f[j] = (_Float16)nw1[(size_t)(kb + j) * OUT_F + colb];
            w1f[kk][nt] = f;
        }
#pragma unroll
    for (int kk = 0; kk < 4; ++kk)
#pragma unroll
        for (int nt = 0; nt < 2; ++nt) {
            half8 f;
            int colb = o0 + nt * 16 + arow;
            int kb = kk * 32 + kg * 8;
#pragma unroll
            for (int j = 0; j < 8; ++j)
                f[j] = (_Float16)nw2[(size_t)(kb + j) * OUT_F + colb];
            w2f[kk][nt] = f;
        }

    const float e0 = 1.f + eps[0], e1 = 1.f + eps[1], e2 = 1.f + eps[2];
    const float b1a = nb1[o0 + arow],      b1b = nb1[o0 + 16 + arow];
    const float b2a = nb2[o0 + arow],      b2b = nb2[o0 + 16 + arow];

    for (int t = blockIdx.x; t < NTILES; t += gridDim.x) {
        const int nb16 = t * 16;
        __syncthreads();   // prev iter fully consumed vtile/htile

        // ---- gather: wave wid accumulates nodes nb16+wid*4 .. +4 ----
#pragma unroll
        for (int q = 0; q < 4; ++q) {
            const int ln = wid * 4 + q;
            const int n  = nb16 + ln;
            const int start = (n == 0) ? 0 : endoff[n - 1];
            const int end   = endoff[n];
            float a0 = 0.f, a1 = 0.f, a2 = 0.f;
            if (start < end) {
                float4 r = sorted[start];
                for (int i = start; i < end; ++i) {
                    float4 rn = (i + 1 < end) ? sorted[i + 1] : r;  // prefetch
                    int src = __float_as_int(r.x);
                    float xj = x[(size_t)src * D_FEAT + lane];
                    a0 = fmaf(r.y, xj, a0);
                    a1 = fmaf(r.z, xj, a1);
                    a2 = fmaf(r.w, xj, a2);
                    r = rn;
                }
            }
            float xn = x[(size_t)n * D_FEAT + lane];
            vtile[ln][lane]       = (_Float16)(a0 + e0 * xn);
            vtile[ln][64 + lane]  = (_Float16)(a1 + e1 * xn);
            vtile[ln][128 + lane] = (_Float16)(a2 + e2 * xn);
        }
        __syncthreads();

        // ---- GEMM1: [16x192] x [192x32] -> h, lrelu ----
        f32x4 acc0 = {0.f, 0.f, 0.f, 0.f}, acc1 = {0.f, 0.f, 0.f, 0.f};
#pragma unroll
        for (int kk = 0; kk < 6; ++kk) {
            half8 a = *(const half8*)&vtile[arow][kk * 32 + kg * 8];
            acc0 = __builtin_amdgcn_mfma_f32_16x16x32_f16(a, w1f[kk][0], acc0, 0, 0, 0);
            acc1 = __builtin_amdgcn_mfma_f32_16x16x32_f16(a, w1f[kk][1], acc1, 0, 0, 0);
        }
#pragma unroll
        for (int r = 0; r < 4; ++r) {
            int hr = kg * 4 + r;
            htile[hr][o0 + arow]      = (_Float16)lrelu(acc0[r] + b1a);
            htile[hr][o0 + 16 + arow] = (_Float16)lrelu(acc1[r] + b1b);
        }
        __syncthreads();

        // ---- GEMM2: [16x128] x [128x32] -> out ----
        f32x4 c0 = {0.f, 0.f, 0.f, 0.f}, c1 = {0.f, 0.f, 0.f, 0.f};
#pragma unroll
        for (int kk = 0; kk < 4; ++kk) {
            half8 a = *(const half8*)&htile[arow][kk * 32 + kg * 8];
            c0 = __builtin_amdgcn_mfma_f32_16x16x32_f16(a, w2f[kk][0], c0, 0, 0, 0);
            c1 = __builtin_amdgcn_mfma_f32_16x16x32_f16(a, w2f[kk][1], c1, 0, 0, 0);
        }
#pragma unroll
        for (int r = 0; r < 4; ++r) {
            size_t n = (size_t)(nb16 + kg * 4 + r);
            out[n * OUT_F + o0 + arow]      = c0[r] + b2a;
            out[n * OUT_F + o0 + 16 + arow] = c1[r] + b2b;
        }
    }
}

extern "C" void kernel_launch(void* const* d_in, const int* in_sizes, int n_in,
                              void* d_out, int out_size, void* d_ws, size_t ws_size,
                              hipStream_t stream)
{
    const float* x    = (const float*)d_in[0];
    const int*   ei   = (const int*)  d_in[1];
    const float* ea   = (const float*)d_in[2];
    const float* w1   = (const float*)d_in[3];
    const float* b1   = (const float*)d_in[4];
    const float* w2   = (const float*)d_in[5];
    const float* b2   = (const float*)d_in[6];
    const float* eps  = (const float*)d_in[7];
    const float* nw1  = (const float*)d_in[8];
    const float* nb1  = (const float*)d_in[9];
    const float* nw2  = (const float*)d_in[10];
    const float* nb2  = (const float*)d_in[11];
    float* out = (float*)d_out;

    // workspace layout
    char* ws = (char*)d_ws;
    int*    counts    = (int*)   (ws + 0);              // 200 KB
    int*    offsets   = (int*)   (ws + (256 << 10));    // 200 KB
    int*    blocksums = (int*)   (ws + (512 << 10));    // <1 KB
    int*    blockoffs = (int*)   (ws + (516 << 10));    // <1 KB
    float4* sorted    = (float4*)(ws + (1 << 20));      // 12.8 MB

    hipMemsetAsync(counts, 0, N_NODES * sizeof(int), stream);

    k_hist     <<<E_EDGES / 256, 256, 0, stream>>>(ei, counts);
    k_blocksum <<<NBLK_SCAN,     256, 0, stream>>>(counts, blocksums);
    k_scanblock<<<1,             256, 0, stream>>>(blocksums, blockoffs);
    k_scanfinal<<<NBLK_SCAN,     256, 0, stream>>>(counts, blockoffs, offsets);
    k_place    <<<E_EDGES / 256, 256, 0, stream>>>(ei, ea, w1, b1, w2, b2, offsets, sorted);
    k_gmlp     <<<768,           256, 0, stream>>>(sorted, offsets, x, eps, nw1, nb1, nw2, nb2, out);
}

// Round 4
// 168.847 us; speedup vs baseline: 4.9895x; 1.6329x over previous
//
#include <hip/hip_runtime.h>
#include <math.h>

#define N_NODES 50000
#define E_EDGES 800000
#define D_FEAT  64
#define C_CH    3
#define H_HID   8
#define OUT_F   128
#define CD      192              // C*D
#define NTILES  (N_NODES / 16)   // 3125 exact
#define NBLK_SCAN ((N_NODES + 255) / 256)   // 196

typedef _Float16 half8 __attribute__((ext_vector_type(8)));
typedef float f32x4 __attribute__((ext_vector_type(4)));

__device__ __forceinline__ float lrelu(float v) { return v >= 0.f ? v : 0.01f * v; }

// --- K1: histogram of dst ---------------------------------------------------
__global__ __launch_bounds__(256) void k_hist(
    const int* __restrict__ ei, int* __restrict__ counts)
{
    int e = blockIdx.x * 256 + threadIdx.x;      // grid covers E exactly
    atomicAdd(counts + ei[E_EDGES + e], 1);
}

// --- K2a: per-block sums of counts ------------------------------------------
__global__ __launch_bounds__(256) void k_blocksum(
    const int* __restrict__ counts, int* __restrict__ blocksums)
{
    __shared__ int s[256];
    int i = blockIdx.x * 256 + threadIdx.x;
    s[threadIdx.x] = (i < N_NODES) ? counts[i] : 0;
    __syncthreads();
    for (int off = 128; off >= 1; off >>= 1) {
        if (threadIdx.x < off) s[threadIdx.x] += s[threadIdx.x + off];
        __syncthreads();
    }
    if (threadIdx.x == 0) blocksums[blockIdx.x] = s[0];
}

// --- K2b: exclusive scan of block sums (single block) -----------------------
__global__ __launch_bounds__(256) void k_scanblock(
    const int* __restrict__ blocksums, int* __restrict__ blockoffs)
{
    __shared__ int s[256];
    int tid = threadIdx.x;
    int v = (tid < NBLK_SCAN) ? blocksums[tid] : 0;
    s[tid] = v;
    __syncthreads();
    for (int off = 1; off < 256; off <<= 1) {
        int t = (tid >= off) ? s[tid - off] : 0;
        __syncthreads();
        s[tid] += t;
        __syncthreads();
    }
    if (tid < NBLK_SCAN) blockoffs[tid] = s[tid] - v;   // exclusive
}

// --- K2c: final exclusive scan ----------------------------------------------
__global__ __launch_bounds__(256) void k_scanfinal(
    const int* __restrict__ counts, const int* __restrict__ blockoffs,
    int* __restrict__ offsets)
{
    __shared__ int s[256];
    int tid = threadIdx.x;
    int i = blockIdx.x * 256 + tid;
    int v = (i < N_NODES) ? counts[i] : 0;
    s[tid] = v;
    __syncthreads();
    for (int off = 1; off < 256; off <<= 1) {
        int t = (tid >= off) ? s[tid - off] : 0;
        __syncthreads();
        s[tid] += t;
        __syncthreads();
    }
    if (i < N_NODES) offsets[i] = s[tid] - v + blockoffs[blockIdx.x];
}

// --- K3: edge MLP + placement into dst-sorted record array ------------------
// after this kernel, offsets[n] has become the END offset of node n.
__global__ __launch_bounds__(256) void k_place(
    const int* __restrict__ ei, const float* __restrict__ ea,
    const float* __restrict__ w1, const float* __restrict__ b1,
    const float* __restrict__ w2, const float* __restrict__ b2,
    int* __restrict__ offsets, float4* __restrict__ sorted)
{
    int e = blockIdx.x * 256 + threadIdx.x;
    int src = ei[e];
    int dst = ei[E_EDGES + e];
    float a = ea[e];
    float wc[C_CH];
#pragma unroll
    for (int c = 0; c < C_CH; ++c) {
        float s = 0.f;
#pragma unroll
        for (int h = 0; h < H_HID; ++h) {
            float t = fmaf(a, w1[c * H_HID + h], b1[c * H_HID + h]);
            t = (t >= 0.f) ? t : 0.01f * t;               // leaky_relu
            s = fmaf(t, w2[c * H_HID + h], s);
        }
        s += b2[c];
        wc[c] = (s > 0.f) ? s : expm1f(s);                // elu
    }
    int pos = atomicAdd(offsets + dst, 1);
    sorted[pos] = make_float4(__int_as_float(src), wc[0], wc[1], wc[2]);
}

// --- K4: gather + residual -> v[N][192] f16 (one wave per node) -------------
__global__ __launch_bounds__(256) void k_gather(
    const float4* __restrict__ sorted, const int* __restrict__ endoff,
    const float* __restrict__ x, const float* __restrict__ eps,
    _Float16* __restrict__ v)
{
    const int n    = blockIdx.x * 4 + (threadIdx.x >> 6);   // 12500*4 = N exact
    const int lane = threadIdx.x & 63;

    const int start = (n == 0) ? 0 : endoff[n - 1];
    const int end   = endoff[n];
    const int len   = end - start;
    const float4* p = sorted + start;

    float a0 = 0.f, a1 = 0.f, a2 = 0.f;   // even-edge chain
    float b0 = 0.f, b1 = 0.f, b2 = 0.f;   // odd-edge chain
    int i = 0;
    for (; i + 2 <= len; i += 2) {
        float4 r0 = p[i], r1 = p[i + 1];
        float x0 = x[(size_t)__float_as_int(r0.x) * D_FEAT + lane];
        float x1 = x[(size_t)__float_as_int(r1.x) * D_FEAT + lane];
        a0 = fmaf(r0.y, x0, a0); a1 = fmaf(r0.z, x0, a1); a2 = fmaf(r0.w, x0, a2);
        b0 = fmaf(r1.y, x1, b0); b1 = fmaf(r1.z, x1, b1); b2 = fmaf(r1.w, x1, b2);
    }
    if (i < len) {
        float4 r0 = p[i];
        float x0 = x[(size_t)__float_as_int(r0.x) * D_FEAT + lane];
        a0 = fmaf(r0.y, x0, a0); a1 = fmaf(r0.z, x0, a1); a2 = fmaf(r0.w, x0, a2);
    }
    float xn = x[(size_t)n * D_FEAT + lane];
    _Float16* vr = v + (size_t)n * CD;
    vr[lane]       = (_Float16)(a0 + b0 + (1.f + eps[0]) * xn);
    vr[64 + lane]  = (_Float16)(a1 + b1 + (1.f + eps[1]) * xn);
    vr[128 + lane] = (_Float16)(a2 + b2 + (1.f + eps[2]) * xn);
}

// --- K5: MLP1(lrelu) + MLP2 via f16 MFMA ------------------------------------
// block = 256 thr = 4 waves; 16 nodes per tile; wave w owns output cols 32w..
__global__ __launch_bounds__(256) void k_mlp(
    const _Float16* __restrict__ v,
    const float* __restrict__ nw1, const float* __restrict__ nb1,
    const float* __restrict__ nw2, const float* __restrict__ nb2,
    float* __restrict__ out)
{
    __shared__ _Float16 vtile[16][CD + 8];     // stride 400B (16B mult)
    __shared__ _Float16 htile[16][OUT_F + 8];  // stride 272B (16B mult)

    const int tid  = threadIdx.x;
    const int lane = tid & 63;
    const int wid  = tid >> 6;
    const int arow = lane & 15;        // A row / C col within 16
    const int kg   = lane >> 4;        // k-group (8 k's each)
    const int o0   = wid * 32;         // this wave's first output col

    // ---- weight B-fragments into registers (once per block) ----
    half8 w1f[6][2], w2f[4][2];
#pragma unroll
    for (int kk = 0; kk < 6; ++kk)
#pragma unroll
        for (int nt = 0; nt < 2; ++nt) {
            half8 f;
            int colb = o0 + nt * 16 + arow;
            int kb = kk * 32 + kg * 8;
#pragma unroll
            for (int j = 0; j < 8; ++j)
                f[j] = (_Float16)nw1[(size_t)(kb + j) * OUT_F + colb];
            w1f[kk][nt] = f;
        }
#pragma unroll
    for (int kk = 0; kk < 4; ++kk)
#pragma unroll
        for (int nt = 0; nt < 2; ++nt) {
            half8 f;
            int colb = o0 + nt * 16 + arow;
            int kb = kk * 32 + kg * 8;
#pragma unroll
            for (int j = 0; j < 8; ++j)
                f[j] = (_Float16)nw2[(size_t)(kb + j) * OUT_F + colb];
            w2f[kk][nt] = f;
        }

    const float b1a = nb1[o0 + arow],      b1b = nb1[o0 + 16 + arow];
    const float b2a = nb2[o0 + arow],      b2b = nb2[o0 + 16 + arow];

    for (int t = blockIdx.x; t < NTILES; t += gridDim.x) {
        const int nb16 = t * 16;
        __syncthreads();   // prev iter fully consumed vtile/htile

        // stage v tile: 16 rows x 192 f16 = 384 chunks of 16B
        for (int i = tid; i < 16 * (CD / 8); i += 256) {    // 384 chunks
            int row = i / (CD / 8), c8 = i % (CD / 8);
            *(half8*)&vtile[row][c8 * 8] =
                *(const half8*)(v + (size_t)(nb16 + row) * CD + c8 * 8);
        }
        __syncthreads();

        // ---- GEMM1: [16x192] x [192x32] -> h, lrelu ----
        f32x4 acc0 = {0.f, 0.f, 0.f, 0.f}, acc1 = {0.f, 0.f, 0.f, 0.f};
#pragma unroll
        for (int kk = 0; kk < 6; ++kk) {
            half8 a = *(const half8*)&vtile[arow][kk * 32 + kg * 8];
            acc0 = __builtin_amdgcn_mfma_f32_16x16x32_f16(a, w1f[kk][0], acc0, 0, 0, 0);
            acc1 = __builtin_amdgcn_mfma_f32_16x16x32_f16(a, w1f[kk][1], acc1, 0, 0, 0);
        }
#pragma unroll
        for (int r = 0; r < 4; ++r) {
            int hr = kg * 4 + r;
            htile[hr][o0 + arow]      = (_Float16)lrelu(acc0[r] + b1a);
            htile[hr][o0 + 16 + arow] = (_Float16)lrelu(acc1[r] + b1b);
        }
        __syncthreads();

        // ---- GEMM2: [16x128] x [128x32] -> out ----
        f32x4 c0 = {0.f, 0.f, 0.f, 0.f}, c1 = {0.f, 0.f, 0.f, 0.f};
#pragma unroll
        for (int kk = 0; kk < 4; ++kk) {
            half8 a = *(const half8*)&htile[arow][kk * 32 + kg * 8];
            c0 = __builtin_amdgcn_mfma_f32_16x16x32_f16(a, w2f[kk][0], c0, 0, 0, 0);
            c1 = __builtin_amdgcn_mfma_f32_16x16x32_f16(a, w2f[kk][1], c1, 0, 0, 0);
        }
#pragma unroll
        for (int r = 0; r < 4; ++r) {
            size_t n = (size_t)(nb16 + kg * 4 + r);
            out[n * OUT_F + o0 + arow]      = c0[r] + b2a;
            out[n * OUT_F + o0 + 16 + arow] = c1[r] + b2b;
        }
    }
}

extern "C" void kernel_launch(void* const* d_in, const int* in_sizes, int n_in,
                              void* d_out, int out_size, void* d_ws, size_t ws_size,
                              hipStream_t stream)
{
    const float* x    = (const float*)d_in[0];
    const int*   ei   = (const int*)  d_in[1];
    const float* ea   = (const float*)d_in[2];
    const float* w1   = (const float*)d_in[3];
    const float* b1   = (const float*)d_in[4];
    const float* w2   = (const float*)d_in[5];
    const float* b2   = (const float*)d_in[6];
    const float* eps  = (const float*)d_in[7];
    const float* nw1  = (const float*)d_in[8];
    const float* nb1  = (const float*)d_in[9];
    const float* nw2  = (const float*)d_in[10];
    const float* nb2  = (const float*)d_in[11];
    float* out = (float*)d_out;

    // workspace layout
    char* ws = (char*)d_ws;
    int*       counts    = (int*)    (ws + 0);              // 200 KB
    int*       offsets   = (int*)    (ws + (256 << 10));    // 200 KB
    int*       blocksums = (int*)    (ws + (512 << 10));    // <1 KB
    int*       blockoffs = (int*)    (ws + (516 << 10));    // <1 KB
    float4*    sorted    = (float4*) (ws + (1 << 20));      // 12.8 MB
    _Float16*  v         = (_Float16*)(ws + (16u << 20));   // 19.2 MB

    hipMemsetAsync(counts, 0, N_NODES * sizeof(int), stream);

    k_hist     <<<E_EDGES / 256, 256, 0, stream>>>(ei, counts);
    k_blocksum <<<NBLK_SCAN,     256, 0, stream>>>(counts, blocksums);
    k_scanblock<<<1,             256, 0, stream>>>(blocksums, blockoffs);
    k_scanfinal<<<NBLK_SCAN,     256, 0, stream>>>(counts, blockoffs, offsets);
    k_place    <<<E_EDGES / 256, 256, 0, stream>>>(ei, ea, w1, b1, w2, b2, offsets, sorted);
    k_gather   <<<N_NODES / 4,   256, 0, stream>>>(sorted, offsets, x, eps, v);
    k_mlp      <<<768,           256, 0, stream>>>(v, nw1, nb1, nw2, nb2, out);
}